// Round 6
// baseline (840.065 us; speedup 1.0000x reference)
//
#include <hip/hip_runtime.h>

#define NN 50000
#define NE 800000
#define DD 128
#define NG 250
#define BN_EPS 1e-5f

#define SCAN_B 256
#define SCAN_CH ((NN + SCAN_B - 1) / SCAN_B)   // 196
#define GATHER_BLOCKS 2048

typedef unsigned short u16;

__device__ inline u16 f2bf(float f) {
    union { float f; unsigned u; } c;
    c.f = f;
    unsigned r = c.u + 0x7fffu + ((c.u >> 16) & 1u);  // RTNE
    return (u16)(r >> 16);
}
__device__ inline float bf_lo(unsigned u) {
    union { unsigned u; float f; } c;
    c.u = u << 16;
    return c.f;
}
__device__ inline float bf_hi(unsigned u) {
    union { unsigned u; float f; } c;
    c.u = u & 0xffff0000u;
    return c.f;
}

// ---------------- CSR build ----------------

__global__ void count_k(const int* __restrict__ dst, int* __restrict__ cnt) {
    int e = blockIdx.x * 256 + threadIdx.x;
    if (e < NE) atomicAdd(&cnt[dst[e]], 1);
}

__global__ __launch_bounds__(256) void sum_k(const int* __restrict__ cnt,
                                             int* __restrict__ bsum) {
    __shared__ int red[256];
    int b = blockIdx.x, t = threadIdx.x;
    int lo = b * SCAN_CH, hi = lo + SCAN_CH;
    if (hi > NN) hi = NN;
    int s = 0;
    for (int i = lo + t; i < hi; i += 256) s += cnt[i];
    red[t] = s;
    __syncthreads();
    for (int off = 128; off > 0; off >>= 1) {
        if (t < off) red[t] += red[t + off];
        __syncthreads();
    }
    if (t == 0) bsum[b] = red[0];
}

__global__ __launch_bounds__(256) void bscan_k(const int* __restrict__ bsum,
                                               int* __restrict__ boff,
                                               int* __restrict__ rs) {
    __shared__ int ss[256];
    int t = threadIdx.x;
    int v = bsum[t];
    ss[t] = v;
    __syncthreads();
    for (int off = 1; off < 256; off <<= 1) {
        int u = (t >= off) ? ss[t - off] : 0;
        __syncthreads();
        ss[t] += u;
        __syncthreads();
    }
    boff[t] = ss[t] - v;
    if (t == 0) rs[NN] = NE;
}

__global__ __launch_bounds__(256) void cscan_k(const int* __restrict__ cnt,
                                               const int* __restrict__ boff,
                                               int* __restrict__ rs,
                                               float* __restrict__ dis) {
    __shared__ int ss[256];
    int b = blockIdx.x, t = threadIdx.x;
    int lo = b * SCAN_CH;
    int i = lo + t;
    int v = (t < SCAN_CH && i < NN) ? cnt[i] : 0;
    ss[t] = v;
    __syncthreads();
    for (int off = 1; off < 256; off <<= 1) {
        int u = (t >= off) ? ss[t - off] : 0;
        __syncthreads();
        ss[t] += u;
        __syncthreads();
    }
    if (t < SCAN_CH && i < NN) {
        rs[i] = ss[t] - v + boff[b];
        float d = (float)(v + 1);
        dis[i] = 1.0f / sqrtf(d);
    }
}

__global__ void fill_k(const int* __restrict__ src, const int* __restrict__ dst,
                       const int* __restrict__ rs, int* __restrict__ fc,
                       int* __restrict__ ssrc) {
    int e = blockIdx.x * 256 + threadIdx.x;
    if (e < NE) {
        int d = dst[e];
        int pos = rs[d] + atomicAdd(&fc[d], 1);
        ssrc[pos] = src[e];
    }
}

// ---------------- GEMM: HB(bf16) = dis[row] * (act(A) @ W) ----------------

__global__ __launch_bounds__(256, 2) void gemm_k(const float* __restrict__ A,
                                                 const float* __restrict__ W,
                                                 const float* __restrict__ sc,
                                                 const float* __restrict__ sh,
                                                 const float* __restrict__ dis,
                                                 u16* __restrict__ HB, int use_bn) {
    __shared__ float As[32 * 128];
    __shared__ float Ws[128 * 128];
    int tid = threadIdx.x;
    int row0 = blockIdx.x * 32;
    {
        const float4* Wg = (const float4*)W;
        float4* Wl = (float4*)Ws;
#pragma unroll
        for (int i = 0; i < 16; i++) Wl[tid + 256 * i] = Wg[tid + 256 * i];
    }
    {
        int r = tid >> 3, cg = (tid & 7) * 16;
        int grow = row0 + r;
        float4* Al = (float4*)(As + r * 128 + cg);
        if (grow < NN) {
            const float4* Ag = (const float4*)(A + (size_t)grow * DD + cg);
            if (use_bn) {
#pragma unroll
                for (int i = 0; i < 4; i++) {
                    float4 v = Ag[i];
                    float4 s4 = *(const float4*)(sc + cg + i * 4);
                    float4 t4 = *(const float4*)(sh + cg + i * 4);
                    v.x = fmaxf(fmaf(v.x, s4.x, t4.x), 0.f);
                    v.y = fmaxf(fmaf(v.y, s4.y, t4.y), 0.f);
                    v.z = fmaxf(fmaf(v.z, s4.z, t4.z), 0.f);
                    v.w = fmaxf(fmaf(v.w, s4.w, t4.w), 0.f);
                    Al[i] = v;
                }
            } else {
#pragma unroll
                for (int i = 0; i < 4; i++) Al[i] = Ag[i];
            }
        } else {
            float4 z = make_float4(0.f, 0.f, 0.f, 0.f);
#pragma unroll
            for (int i = 0; i < 4; i++) Al[i] = z;
        }
    }
    __syncthreads();
    int tx = tid & 31, ty = tid >> 5;
    float4 acc[4];
#pragma unroll
    for (int r = 0; r < 4; r++) acc[r] = make_float4(0.f, 0.f, 0.f, 0.f);
#pragma unroll 8
    for (int k = 0; k < DD; k++) {
        float4 w = *(const float4*)(Ws + k * DD + tx * 4);
#pragma unroll
        for (int r = 0; r < 4; r++) {
            float a = As[(ty + 8 * r) * DD + k];
            acc[r].x = fmaf(a, w.x, acc[r].x);
            acc[r].y = fmaf(a, w.y, acc[r].y);
            acc[r].z = fmaf(a, w.z, acc[r].z);
            acc[r].w = fmaf(a, w.w, acc[r].w);
        }
    }
#pragma unroll
    for (int r = 0; r < 4; r++) {
        int grow = row0 + ty + 8 * r;
        if (grow < NN) {
            float dv = dis[grow];
            ushort4 o;
            o.x = f2bf(acc[r].x * dv);
            o.y = f2bf(acc[r].y * dv);
            o.z = f2bf(acc[r].z * dv);
            o.w = f2bf(acc[r].w * dv);
            *(ushort4*)(HB + (size_t)grow * DD + tx * 4) = o;
        }
    }
}

// ---------------- Gather pass: 32 channels (L2-resident working set) ----------------
// out[v, cb..cb+31] = dis[v] * (sum_{s in N(v)} HB[s] + HB[v]) + bias
// Wave layout: 4 edge-groups x 16 channel-lanes (2 bf16 channels per lane).
// NOTE: every __shfl executes under wave-uniform control flow (tail guard is
// uniform in `tail`); only the dependent loads/adds are lane-predicated.

__global__ __launch_bounds__(256) void gatherp_k(const u16* __restrict__ HB,
                                                 const float* __restrict__ dis,
                                                 const int* __restrict__ rs,
                                                 const int* __restrict__ ssrc,
                                                 const float* __restrict__ bias,
                                                 float* __restrict__ AGG,
                                                 float* __restrict__ stats,
                                                 int cb) {
    __shared__ float s_sum[32], s_sq[32];
    int tid = threadIdx.x;
    if (tid < 32) { s_sum[tid] = 0.f; s_sq[tid] = 0.f; }
    __syncthreads();
    int lane = tid & 63;
    int eg = lane >> 4;      // edge subgroup 0..3
    int cl = lane & 15;      // channel lane 0..15
    int c = cb + cl * 2;     // absolute channel
    int wid = blockIdx.x * 4 + (tid >> 6);
    const int nwaves = GATHER_BLOCKS * 4;
    float b0 = bias[c], b1 = bias[c + 1];
    float lsum0 = 0.f, lsum1 = 0.f, lsq0 = 0.f, lsq1 = 0.f;
    for (int v = wid; v < NN; v += nwaves) {
        int start = rs[v], end = rs[v + 1];
        float a0 = 0.f, a1 = 0.f;
        for (int base = start; base < end; base += 64) {
            int rem = end - base;
            int cnt = rem < 64 ? rem : 64;
            int myidx = (lane < cnt) ? ssrc[base + lane] : 0;
            int j = 0;
            for (; (j + 4) * 4 <= cnt; j += 4) {   // 16 edges per iter, uniform flow
                int e0 = j * 4 + eg;
                int s0 = __shfl(myidx, e0);
                int s1 = __shfl(myidx, e0 + 4);
                int s2 = __shfl(myidx, e0 + 8);
                int s3 = __shfl(myidx, e0 + 12);
                unsigned r0 = *(const unsigned*)(HB + (size_t)s0 * DD + c);
                unsigned r1 = *(const unsigned*)(HB + (size_t)s1 * DD + c);
                unsigned r2 = *(const unsigned*)(HB + (size_t)s2 * DD + c);
                unsigned r3 = *(const unsigned*)(HB + (size_t)s3 * DD + c);
                a0 += bf_lo(r0) + bf_lo(r1) + bf_lo(r2) + bf_lo(r3);
                a1 += bf_hi(r0) + bf_hi(r1) + bf_hi(r2) + bf_hi(r3);
            }
            for (; (j + 1) * 4 <= cnt; j++) {      // 4 edges per iter, uniform flow
                int s0 = __shfl(myidx, j * 4 + eg);
                unsigned r0 = *(const unsigned*)(HB + (size_t)s0 * DD + c);
                a0 += bf_lo(r0);
                a1 += bf_hi(r0);
            }
            int tail = cnt - j * 4;                // 0..3 edges; tail is wave-uniform
            if (tail) {                            // uniform branch: all lanes enter
                int s0 = __shfl(myidx, j * 4 + eg);  // sources lane<cnt, all active
                if (eg < tail) {                   // lane-predicated load+add only
                    unsigned r0 = *(const unsigned*)(HB + (size_t)s0 * DD + c);
                    a0 += bf_lo(r0);
                    a1 += bf_hi(r0);
                }
            }
        }
        // reduce across the 4 edge-groups (uniform flow)
        a0 += __shfl_xor(a0, 16); a0 += __shfl_xor(a0, 32);
        a1 += __shfl_xor(a1, 16); a1 += __shfl_xor(a1, 32);
        if (eg == 0) {
            unsigned rsf = *(const unsigned*)(HB + (size_t)v * DD + c);
            float dv = dis[v];
            float o0 = fmaf(a0 + bf_lo(rsf), dv, b0);
            float o1 = fmaf(a1 + bf_hi(rsf), dv, b1);
            *(float2*)(AGG + (size_t)v * DD + c) = make_float2(o0, o1);
            lsum0 += o0; lsum1 += o1;
            lsq0 += o0 * o0; lsq1 += o1 * o1;
        }
    }
    if (eg == 0) {
        atomicAdd(&s_sum[cl * 2], lsum0);
        atomicAdd(&s_sum[cl * 2 + 1], lsum1);
        atomicAdd(&s_sq[cl * 2], lsq0);
        atomicAdd(&s_sq[cl * 2 + 1], lsq1);
    }
    __syncthreads();
    if (tid < 32) {
        atomicAdd(&stats[cb + tid], s_sum[tid]);
        atomicAdd(&stats[128 + cb + tid], s_sq[tid]);
    }
}

// ---------------- BN stats -> scale/shift ----------------

__global__ void bnfix_k(const float* __restrict__ stats, const float* __restrict__ g,
                        const float* __restrict__ be, float* __restrict__ sc,
                        float* __restrict__ sh) {
    int c = threadIdx.x;
    float mean = stats[c] * (1.0f / NN);
    float var = stats[128 + c] * (1.0f / NN) - mean * mean;
    float s = g[c] / sqrtf(var + BN_EPS);
    sc[c] = s;
    sh[c] = be[c] - mean * s;
}

// ---------------- Pool ----------------

__global__ __launch_bounds__(256) void pool_k(const float* __restrict__ AGG,
                                              const int* __restrict__ batch,
                                              const float* __restrict__ sc,
                                              const float* __restrict__ sh,
                                              float* __restrict__ P) {
    int lane = threadIdx.x & 63;
    int wid = blockIdx.x * 4 + (threadIdx.x >> 6);
    int nw = gridDim.x * 4;
    int c = lane * 2;
    float sc0 = sc[c], sc1 = sc[c + 1], sh0 = sh[c], sh1 = sh[c + 1];
    int chunk = (NN + nw - 1) / nw;
    int v0 = wid * chunk, v1 = v0 + chunk;
    if (v1 > NN) v1 = NN;
    if (v0 >= NN) return;
    int curb = batch[v0];
    float acc0 = 0.f, acc1 = 0.f;
    for (int v = v0; v < v1; v++) {
        int b = batch[v];
        if (b != curb) {
            atomicAdd(&P[curb * 128 + c], acc0);
            atomicAdd(&P[curb * 128 + c + 1], acc1);
            acc0 = 0.f; acc1 = 0.f; curb = b;
        }
        float2 hv = *(const float2*)(AGG + (size_t)v * DD + c);
        acc0 += fmaxf(fmaf(hv.x, sc0, sh0), 0.f);
        acc1 += fmaxf(fmaf(hv.y, sc1, sh1), 0.f);
    }
    atomicAdd(&P[curb * 128 + c], acc0);
    atomicAdd(&P[curb * 128 + c + 1], acc1);
}

// ---------------- Head ----------------

__global__ __launch_bounds__(128) void head_k(const float* __restrict__ P,
                                              const float* __restrict__ Wm1,
                                              const float* __restrict__ bm1,
                                              const float* __restrict__ Wm2,
                                              const float* __restrict__ bm2,
                                              float* __restrict__ OUT) {
    __shared__ float prow[128];
    __shared__ float red[128];
    int g = blockIdx.x, t = threadIdx.x;
    prow[t] = P[g * 128 + t];
    __syncthreads();
    float acc = bm1[t];
#pragma unroll 8
    for (int i = 0; i < 128; i++) acc = fmaf(prow[i], Wm1[i * 128 + t], acc);
    red[t] = fmaxf(acc, 0.f) * Wm2[t];
    __syncthreads();
    for (int off = 64; off > 0; off >>= 1) {
        if (t < off) red[t] += red[t + off];
        __syncthreads();
    }
    if (t == 0) OUT[g] = red[0] + bm2[0];
}

// ---------------- Launch ----------------

extern "C" void kernel_launch(void* const* d_in, const int* in_sizes, int n_in,
                              void* d_out, int out_size, void* d_ws, size_t ws_size,
                              hipStream_t stream) {
    const float* x   = (const float*)d_in[0];
    const int*  ei   = (const int*)d_in[1];
    const int*  batch= (const int*)d_in[2];
    const float* W1  = (const float*)d_in[3];
    const float* b1  = (const float*)d_in[4];
    const float* g1  = (const float*)d_in[5];
    const float* be1 = (const float*)d_in[6];
    const float* W2  = (const float*)d_in[7];
    const float* b2  = (const float*)d_in[8];
    const float* g2  = (const float*)d_in[9];
    const float* be2 = (const float*)d_in[10];
    const float* W3  = (const float*)d_in[11];
    const float* b3  = (const float*)d_in[12];
    const float* g3  = (const float*)d_in[13];
    const float* be3 = (const float*)d_in[14];
    const float* Wm1 = (const float*)d_in[15];
    const float* bm1 = (const float*)d_in[16];
    const float* Wm2 = (const float*)d_in[17];
    const float* bm2 = (const float*)d_in[18];
    float* out = (float*)d_out;

    char* ws = (char*)d_ws;
    size_t off = 0;
    auto alloc = [&](size_t bytes) -> void* {
        void* p = ws + off;
        off = (off + bytes + 255) & ~(size_t)255;
        return p;
    };
    int*   cnt   = (int*)alloc((size_t)NN * 4);
    int*   rs    = (int*)alloc((size_t)(NN + 1) * 4);
    int*   fc    = (int*)alloc((size_t)NN * 4);
    float* dis   = (float*)alloc((size_t)NN * 4);
    int*   ssrc  = (int*)alloc((size_t)NE * 4);
    u16*   hb    = (u16*)alloc((size_t)NN * DD * 2);
    float* agg   = (float*)alloc((size_t)NN * DD * 4);
    float* stats = (float*)alloc(3 * 256 * 4);
    float* scb   = (float*)alloc(3 * 128 * 4);
    float* shb   = (float*)alloc(3 * 128 * 4);
    float* p     = (float*)alloc((size_t)NG * DD * 4);
    int*   bsum  = (int*)alloc(SCAN_B * 4);
    int*   boff  = (int*)alloc(SCAN_B * 4);

    const int* srcI = ei;
    const int* dstI = ei + NE;

    hipMemsetAsync(cnt, 0, (size_t)NN * 4, stream);
    hipMemsetAsync(fc, 0, (size_t)NN * 4, stream);
    hipMemsetAsync(stats, 0, 3 * 256 * 4, stream);
    hipMemsetAsync(p, 0, (size_t)NG * DD * 4, stream);

    count_k<<<(NE + 255) / 256, 256, 0, stream>>>(dstI, cnt);
    sum_k<<<SCAN_B, 256, 0, stream>>>(cnt, bsum);
    bscan_k<<<1, 256, 0, stream>>>(bsum, boff, rs);
    cscan_k<<<SCAN_B, 256, 0, stream>>>(cnt, boff, rs, dis);
    fill_k<<<(NE + 255) / 256, 256, 0, stream>>>(srcI, dstI, rs, fc, ssrc);

    const int GB = (NN + 31) / 32;

    // Layer 1
    gemm_k<<<GB, 256, 0, stream>>>(x, W1, nullptr, nullptr, dis, hb, 0);
    for (int ps = 0; ps < 4; ++ps)
        gatherp_k<<<GATHER_BLOCKS, 256, 0, stream>>>(hb, dis, rs, ssrc, b1, agg, stats, ps * 32);
    bnfix_k<<<1, 128, 0, stream>>>(stats, g1, be1, scb, shb);

    // Layer 2
    gemm_k<<<GB, 256, 0, stream>>>(agg, W2, scb, shb, dis, hb, 1);
    for (int ps = 0; ps < 4; ++ps)
        gatherp_k<<<GATHER_BLOCKS, 256, 0, stream>>>(hb, dis, rs, ssrc, b2, agg, stats + 256, ps * 32);
    bnfix_k<<<1, 128, 0, stream>>>(stats + 256, g2, be2, scb + 128, shb + 128);

    // Layer 3
    gemm_k<<<GB, 256, 0, stream>>>(agg, W3, scb + 128, shb + 128, dis, hb, 1);
    for (int ps = 0; ps < 4; ++ps)
        gatherp_k<<<GATHER_BLOCKS, 256, 0, stream>>>(hb, dis, rs, ssrc, b3, agg, stats + 512, ps * 32);
    bnfix_k<<<1, 128, 0, stream>>>(stats + 512, g3, be3, scb + 256, shb + 256);

    // Pool + head
    pool_k<<<128, 256, 0, stream>>>(agg, batch, scb + 256, shb + 256, p);
    head_k<<<NG, 128, 0, stream>>>(p, Wm1, bm1, Wm2, bm2, out);
}

// Round 7
// 604.103 us; speedup vs baseline: 1.3906x; 1.3906x over previous
//
#include <hip/hip_runtime.h>

#define NN 50000
#define NE 800000
#define DD 128
#define NG 250
#define BN_EPS 1e-5f

#define SCAN_B 256
#define SCAN_CH ((NN + SCAN_B - 1) / SCAN_B)   // 196
#define GATHER_BLOCKS 2048

typedef unsigned short u16;

__device__ inline u16 f2bf(float f) {
    union { float f; unsigned u; } c;
    c.f = f;
    unsigned r = c.u + 0x7fffu + ((c.u >> 16) & 1u);  // RTNE
    return (u16)(r >> 16);
}
__device__ inline unsigned pack2bf(float lo, float hi) {
    return (unsigned)f2bf(lo) | ((unsigned)f2bf(hi) << 16);
}
__device__ inline float bf_lo(unsigned u) {
    union { unsigned u; float f; } c;
    c.u = u << 16;
    return c.f;
}
__device__ inline float bf_hi(unsigned u) {
    union { unsigned u; float f; } c;
    c.u = u & 0xffff0000u;
    return c.f;
}

// ---------------- CSR build ----------------

__global__ void count_k(const int* __restrict__ dst, int* __restrict__ cnt) {
    int e = blockIdx.x * 256 + threadIdx.x;
    if (e < NE) atomicAdd(&cnt[dst[e]], 1);
}

__global__ __launch_bounds__(256) void sum_k(const int* __restrict__ cnt,
                                             int* __restrict__ bsum) {
    __shared__ int red[256];
    int b = blockIdx.x, t = threadIdx.x;
    int lo = b * SCAN_CH, hi = lo + SCAN_CH;
    if (hi > NN) hi = NN;
    int s = 0;
    for (int i = lo + t; i < hi; i += 256) s += cnt[i];
    red[t] = s;
    __syncthreads();
    for (int off = 128; off > 0; off >>= 1) {
        if (t < off) red[t] += red[t + off];
        __syncthreads();
    }
    if (t == 0) bsum[b] = red[0];
}

__global__ __launch_bounds__(256) void bscan_k(const int* __restrict__ bsum,
                                               int* __restrict__ boff,
                                               int* __restrict__ rs) {
    __shared__ int ss[256];
    int t = threadIdx.x;
    int v = bsum[t];
    ss[t] = v;
    __syncthreads();
    for (int off = 1; off < 256; off <<= 1) {
        int u = (t >= off) ? ss[t - off] : 0;
        __syncthreads();
        ss[t] += u;
        __syncthreads();
    }
    boff[t] = ss[t] - v;
    if (t == 0) rs[NN] = NE;
}

__global__ __launch_bounds__(256) void cscan_k(const int* __restrict__ cnt,
                                               const int* __restrict__ boff,
                                               int* __restrict__ rs,
                                               float* __restrict__ dis) {
    __shared__ int ss[256];
    int b = blockIdx.x, t = threadIdx.x;
    int lo = b * SCAN_CH;
    int i = lo + t;
    int v = (t < SCAN_CH && i < NN) ? cnt[i] : 0;
    ss[t] = v;
    __syncthreads();
    for (int off = 1; off < 256; off <<= 1) {
        int u = (t >= off) ? ss[t - off] : 0;
        __syncthreads();
        ss[t] += u;
        __syncthreads();
    }
    if (t < SCAN_CH && i < NN) {
        rs[i] = ss[t] - v + boff[b];
        float d = (float)(v + 1);
        dis[i] = 1.0f / sqrtf(d);
    }
}

__global__ void fill_k(const int* __restrict__ src, const int* __restrict__ dst,
                       const int* __restrict__ rs, int* __restrict__ fc,
                       u16* __restrict__ ssrc) {
    int e = blockIdx.x * 256 + threadIdx.x;
    if (e < NE) {
        int d = dst[e];
        int pos = rs[d] + atomicAdd(&fc[d], 1);
        ssrc[pos] = (u16)src[e];
    }
}

// ---------------- GEMM: HB(bf16) = dis[row] * (act(A) @ W) ----------------
// use_bn=0: A32 fp32 input (layer 1).  use_bn=1: A16 bf16 agg + BN+ReLU fused.

__global__ __launch_bounds__(256, 2) void gemm_k(const float* __restrict__ A32,
                                                 const u16* __restrict__ A16,
                                                 const float* __restrict__ W,
                                                 const float* __restrict__ sc,
                                                 const float* __restrict__ sh,
                                                 const float* __restrict__ dis,
                                                 u16* __restrict__ HB, int use_bn) {
    __shared__ float As[32 * 128];
    __shared__ float Ws[128 * 128];
    int tid = threadIdx.x;
    int row0 = blockIdx.x * 32;
    {
        const float4* Wg = (const float4*)W;
        float4* Wl = (float4*)Ws;
#pragma unroll
        for (int i = 0; i < 16; i++) Wl[tid + 256 * i] = Wg[tid + 256 * i];
    }
    {
        int r = tid >> 3, cg = (tid & 7) * 16;
        int grow = row0 + r;
        float4* Al = (float4*)(As + r * 128 + cg);
        if (grow < NN) {
            if (use_bn) {
                const uint4* Ag = (const uint4*)(A16 + (size_t)grow * DD + cg);
                uint4 q0 = Ag[0], q1 = Ag[1];   // 16 bf16 channels
                unsigned w[8] = {q0.x, q0.y, q0.z, q0.w, q1.x, q1.y, q1.z, q1.w};
#pragma unroll
                for (int i = 0; i < 4; i++) {
                    float4 s4 = *(const float4*)(sc + cg + i * 4);
                    float4 t4 = *(const float4*)(sh + cg + i * 4);
                    float4 v;
                    v.x = fmaxf(fmaf(bf_lo(w[i * 2]),     s4.x, t4.x), 0.f);
                    v.y = fmaxf(fmaf(bf_hi(w[i * 2]),     s4.y, t4.y), 0.f);
                    v.z = fmaxf(fmaf(bf_lo(w[i * 2 + 1]), s4.z, t4.z), 0.f);
                    v.w = fmaxf(fmaf(bf_hi(w[i * 2 + 1]), s4.w, t4.w), 0.f);
                    Al[i] = v;
                }
            } else {
                const float4* Ag = (const float4*)(A32 + (size_t)grow * DD + cg);
#pragma unroll
                for (int i = 0; i < 4; i++) Al[i] = Ag[i];
            }
        } else {
            float4 z = make_float4(0.f, 0.f, 0.f, 0.f);
#pragma unroll
            for (int i = 0; i < 4; i++) Al[i] = z;
        }
    }
    __syncthreads();
    int tx = tid & 31, ty = tid >> 5;
    float4 acc[4];
#pragma unroll
    for (int r = 0; r < 4; r++) acc[r] = make_float4(0.f, 0.f, 0.f, 0.f);
#pragma unroll 8
    for (int k = 0; k < DD; k++) {
        float4 w = *(const float4*)(Ws + k * DD + tx * 4);
#pragma unroll
        for (int r = 0; r < 4; r++) {
            float a = As[(ty + 8 * r) * DD + k];
            acc[r].x = fmaf(a, w.x, acc[r].x);
            acc[r].y = fmaf(a, w.y, acc[r].y);
            acc[r].z = fmaf(a, w.z, acc[r].z);
            acc[r].w = fmaf(a, w.w, acc[r].w);
        }
    }
#pragma unroll
    for (int r = 0; r < 4; r++) {
        int grow = row0 + ty + 8 * r;
        if (grow < NN) {
            float dv = dis[grow];
            ushort4 o;
            o.x = f2bf(acc[r].x * dv);
            o.y = f2bf(acc[r].y * dv);
            o.z = f2bf(acc[r].z * dv);
            o.w = f2bf(acc[r].w * dv);
            *(ushort4*)(HB + (size_t)grow * DD + tx * 4) = o;
        }
    }
}

// ---------------- Gather (pre-scaled bf16 rows) + self-loop + bias + BN stats ----------------
// out[v] = dis[v] * (sum_{s in N(v)} HB[s] + HB[v]) + bias ; AGG stored bf16.
// One wave per node; 64 lanes cover 128 channels; 16 row-loads in flight.

__global__ __launch_bounds__(256) void gather_k(const u16* __restrict__ HB,
                                                const float* __restrict__ dis,
                                                const int* __restrict__ rs,
                                                const u16* __restrict__ ssrc,
                                                const float* __restrict__ bias,
                                                u16* __restrict__ AGG,
                                                float* __restrict__ stats) {
    __shared__ float s_sum[128], s_sq[128];
    int tid = threadIdx.x;
    if (tid < 128) { s_sum[tid] = 0.f; s_sq[tid] = 0.f; }
    __syncthreads();
    int lane = tid & 63;
    int wid = blockIdx.x * 4 + (tid >> 6);
    const int nwaves = GATHER_BLOCKS * 4;
    int c = lane * 2;
    float b0 = bias[c], b1 = bias[c + 1];
    float lsum0 = 0.f, lsum1 = 0.f, lsq0 = 0.f, lsq1 = 0.f;
    for (int v = wid; v < NN; v += nwaves) {
        int start = rs[v], end = rs[v + 1];
        float a0 = 0.f, a1 = 0.f;
        for (int base = start; base < end; base += 64) {
            int rem = end - base;
            int cnt = rem < 64 ? rem : 64;
            int myidx = (lane < cnt) ? (int)ssrc[base + lane] : 0;
            int j = 0;
            for (; j + 16 <= cnt; j += 16) {   // 16 loads in flight
                unsigned r[16];
#pragma unroll
                for (int q = 0; q < 16; q++) {
                    int s = __shfl(myidx, j + q);
                    r[q] = *(const unsigned*)(HB + (size_t)s * DD + c);
                }
#pragma unroll
                for (int q = 0; q < 16; q++) { a0 += bf_lo(r[q]); a1 += bf_hi(r[q]); }
            }
            for (; j + 8 <= cnt; j += 8) {
                unsigned r[8];
#pragma unroll
                for (int q = 0; q < 8; q++) {
                    int s = __shfl(myidx, j + q);
                    r[q] = *(const unsigned*)(HB + (size_t)s * DD + c);
                }
#pragma unroll
                for (int q = 0; q < 8; q++) { a0 += bf_lo(r[q]); a1 += bf_hi(r[q]); }
            }
            for (; j < cnt; j++) {
                int s = __shfl(myidx, j);
                unsigned r0 = *(const unsigned*)(HB + (size_t)s * DD + c);
                a0 += bf_lo(r0);
                a1 += bf_hi(r0);
            }
        }
        unsigned rsf = *(const unsigned*)(HB + (size_t)v * DD + c);
        float dv = dis[v];
        float o0 = fmaf(a0 + bf_lo(rsf), dv, b0);
        float o1 = fmaf(a1 + bf_hi(rsf), dv, b1);
        *(unsigned*)(AGG + (size_t)v * DD + c) = pack2bf(o0, o1);
        lsum0 += o0; lsum1 += o1;
        lsq0 += o0 * o0; lsq1 += o1 * o1;
    }
    atomicAdd(&s_sum[c], lsum0);
    atomicAdd(&s_sum[c + 1], lsum1);
    atomicAdd(&s_sq[c], lsq0);
    atomicAdd(&s_sq[c + 1], lsq1);
    __syncthreads();
    if (tid < 128) {
        atomicAdd(&stats[tid], s_sum[tid]);
        atomicAdd(&stats[128 + tid], s_sq[tid]);
    }
}

// ---------------- BN stats -> scale/shift ----------------

__global__ void bnfix_k(const float* __restrict__ stats, const float* __restrict__ g,
                        const float* __restrict__ be, float* __restrict__ sc,
                        float* __restrict__ sh) {
    int c = threadIdx.x;
    float mean = stats[c] * (1.0f / NN);
    float var = stats[128 + c] * (1.0f / NN) - mean * mean;
    float s = g[c] / sqrtf(var + BN_EPS);
    sc[c] = s;
    sh[c] = be[c] - mean * s;
}

// ---------------- Pool (bf16 agg) ----------------

__global__ __launch_bounds__(256) void pool_k(const u16* __restrict__ AGG,
                                              const int* __restrict__ batch,
                                              const float* __restrict__ sc,
                                              const float* __restrict__ sh,
                                              float* __restrict__ P) {
    int lane = threadIdx.x & 63;
    int wid = blockIdx.x * 4 + (threadIdx.x >> 6);
    int nw = gridDim.x * 4;
    int c = lane * 2;
    float sc0 = sc[c], sc1 = sc[c + 1], sh0 = sh[c], sh1 = sh[c + 1];
    int chunk = (NN + nw - 1) / nw;
    int v0 = wid * chunk, v1 = v0 + chunk;
    if (v1 > NN) v1 = NN;
    if (v0 >= NN) return;
    int curb = batch[v0];
    float acc0 = 0.f, acc1 = 0.f;
    for (int v = v0; v < v1; v++) {
        int b = batch[v];
        if (b != curb) {
            atomicAdd(&P[curb * 128 + c], acc0);
            atomicAdd(&P[curb * 128 + c + 1], acc1);
            acc0 = 0.f; acc1 = 0.f; curb = b;
        }
        unsigned hv = *(const unsigned*)(AGG + (size_t)v * DD + c);
        acc0 += fmaxf(fmaf(bf_lo(hv), sc0, sh0), 0.f);
        acc1 += fmaxf(fmaf(bf_hi(hv), sc1, sh1), 0.f);
    }
    atomicAdd(&P[curb * 128 + c], acc0);
    atomicAdd(&P[curb * 128 + c + 1], acc1);
}

// ---------------- Head ----------------

__global__ __launch_bounds__(128) void head_k(const float* __restrict__ P,
                                              const float* __restrict__ Wm1,
                                              const float* __restrict__ bm1,
                                              const float* __restrict__ Wm2,
                                              const float* __restrict__ bm2,
                                              float* __restrict__ OUT) {
    __shared__ float prow[128];
    __shared__ float red[128];
    int g = blockIdx.x, t = threadIdx.x;
    prow[t] = P[g * 128 + t];
    __syncthreads();
    float acc = bm1[t];
#pragma unroll 8
    for (int i = 0; i < 128; i++) acc = fmaf(prow[i], Wm1[i * 128 + t], acc);
    red[t] = fmaxf(acc, 0.f) * Wm2[t];
    __syncthreads();
    for (int off = 64; off > 0; off >>= 1) {
        if (t < off) red[t] += red[t + off];
        __syncthreads();
    }
    if (t == 0) OUT[g] = red[0] + bm2[0];
}

// ---------------- Launch ----------------

extern "C" void kernel_launch(void* const* d_in, const int* in_sizes, int n_in,
                              void* d_out, int out_size, void* d_ws, size_t ws_size,
                              hipStream_t stream) {
    const float* x   = (const float*)d_in[0];
    const int*  ei   = (const int*)d_in[1];
    const int*  batch= (const int*)d_in[2];
    const float* W1  = (const float*)d_in[3];
    const float* b1  = (const float*)d_in[4];
    const float* g1  = (const float*)d_in[5];
    const float* be1 = (const float*)d_in[6];
    const float* W2  = (const float*)d_in[7];
    const float* b2  = (const float*)d_in[8];
    const float* g2  = (const float*)d_in[9];
    const float* be2 = (const float*)d_in[10];
    const float* W3  = (const float*)d_in[11];
    const float* b3  = (const float*)d_in[12];
    const float* g3  = (const float*)d_in[13];
    const float* be3 = (const float*)d_in[14];
    const float* Wm1 = (const float*)d_in[15];
    const float* bm1 = (const float*)d_in[16];
    const float* Wm2 = (const float*)d_in[17];
    const float* bm2 = (const float*)d_in[18];
    float* out = (float*)d_out;

    char* ws = (char*)d_ws;
    size_t off = 0;
    auto alloc = [&](size_t bytes) -> void* {
        void* p = ws + off;
        off = (off + bytes + 255) & ~(size_t)255;
        return p;
    };
    int*   cnt   = (int*)alloc((size_t)NN * 4);
    int*   rs    = (int*)alloc((size_t)(NN + 1) * 4);
    int*   fc    = (int*)alloc((size_t)NN * 4);
    float* dis   = (float*)alloc((size_t)NN * 4);
    u16*   ssrc  = (u16*)alloc((size_t)NE * 2);
    u16*   hb    = (u16*)alloc((size_t)NN * DD * 2);
    u16*   agg   = (u16*)alloc((size_t)NN * DD * 2);
    float* stats = (float*)alloc(3 * 256 * 4);
    float* scb   = (float*)alloc(3 * 128 * 4);
    float* shb   = (float*)alloc(3 * 128 * 4);
    float* p     = (float*)alloc((size_t)NG * DD * 4);
    int*   bsum  = (int*)alloc(SCAN_B * 4);
    int*   boff  = (int*)alloc(SCAN_B * 4);

    const int* srcI = ei;
    const int* dstI = ei + NE;

    hipMemsetAsync(cnt, 0, (size_t)NN * 4, stream);
    hipMemsetAsync(fc, 0, (size_t)NN * 4, stream);
    hipMemsetAsync(stats, 0, 3 * 256 * 4, stream);
    hipMemsetAsync(p, 0, (size_t)NG * DD * 4, stream);

    count_k<<<(NE + 255) / 256, 256, 0, stream>>>(dstI, cnt);
    sum_k<<<SCAN_B, 256, 0, stream>>>(cnt, bsum);
    bscan_k<<<1, 256, 0, stream>>>(bsum, boff, rs);
    cscan_k<<<SCAN_B, 256, 0, stream>>>(cnt, boff, rs, dis);
    fill_k<<<(NE + 255) / 256, 256, 0, stream>>>(srcI, dstI, rs, fc, ssrc);

    const int GB = (NN + 31) / 32;

    // Layer 1
    gemm_k<<<GB, 256, 0, stream>>>(x, nullptr, W1, nullptr, nullptr, dis, hb, 0);
    gather_k<<<GATHER_BLOCKS, 256, 0, stream>>>(hb, dis, rs, ssrc, b1, agg, stats);
    bnfix_k<<<1, 128, 0, stream>>>(stats, g1, be1, scb, shb);

    // Layer 2
    gemm_k<<<GB, 256, 0, stream>>>(nullptr, agg, W2, scb, shb, dis, hb, 1);
    gather_k<<<GATHER_BLOCKS, 256, 0, stream>>>(hb, dis, rs, ssrc, b2, agg, stats + 256);
    bnfix_k<<<1, 128, 0, stream>>>(stats + 256, g2, be2, scb + 128, shb + 128);

    // Layer 3
    gemm_k<<<GB, 256, 0, stream>>>(nullptr, agg, W3, scb + 128, shb + 128, dis, hb, 1);
    gather_k<<<GATHER_BLOCKS, 256, 0, stream>>>(hb, dis, rs, ssrc, b3, agg, stats + 512);
    bnfix_k<<<1, 128, 0, stream>>>(stats + 512, g3, be3, scb + 256, shb + 256);

    // Pool + head
    pool_k<<<128, 256, 0, stream>>>(agg, batch, scb + 256, shb + 256, p);
    head_k<<<NG, 128, 0, stream>>>(p, Wm1, bm1, Wm2, bm2, out);
}

// Round 8
// 560.382 us; speedup vs baseline: 1.4991x; 1.0780x over previous
//
#include <hip/hip_runtime.h>

#define NN 50000
#define NE 800000
#define DD 128
#define NG 250
#define BN_EPS 1e-5f
#define ELLW 64
#define GATHER_BLOCKS 2048

typedef unsigned short u16;
typedef __attribute__((ext_vector_type(8))) short bf16x8;
typedef __attribute__((ext_vector_type(4))) float f32x4;

__device__ inline u16 f2bf(float f) {
    union { float f; unsigned u; } c;
    c.f = f;
    unsigned r = c.u + 0x7fffu + ((c.u >> 16) & 1u);  // RTNE
    return (u16)(r >> 16);
}
__device__ inline float bf2f(u16 h) {
    union { unsigned u; float f; } c;
    c.u = (unsigned)h << 16;
    return c.f;
}
__device__ inline unsigned pack2bf(float lo, float hi) {
    return (unsigned)f2bf(lo) | ((unsigned)f2bf(hi) << 16);
}
__device__ inline float bf_lo(unsigned u) {
    union { unsigned u; float f; } c;
    c.u = u << 16;
    return c.f;
}
__device__ inline float bf_hi(unsigned u) {
    union { unsigned u; float f; } c;
    c.u = u & 0xffff0000u;
    return c.f;
}

// ---------------- ELL build (no CSR, no scans) ----------------

__global__ void fillell_k(const int* __restrict__ src, const int* __restrict__ dst,
                          int* __restrict__ fc, u16* __restrict__ ell) {
    int e = blockIdx.x * 256 + threadIdx.x;
    if (e < NE) {
        int d = dst[e];
        int pos = atomicAdd(&fc[d], 1);
        if (pos < ELLW) ell[(size_t)d * ELLW + pos] = (u16)src[e];
    }
}

__global__ void dis_k(const int* __restrict__ fc, float* __restrict__ dis) {
    int i = blockIdx.x * 256 + threadIdx.x;
    if (i < NN) dis[i] = 1.0f / sqrtf((float)(fc[i] + 1));
}

// ---------------- W prep: W(fp32 [k][n]) -> WhiT,WloT (bf16 [n][k]) ----------------

__global__ void wprep_k(const float* __restrict__ W1, const float* __restrict__ W2,
                        const float* __restrict__ W3, u16* __restrict__ wt) {
    int lid = blockIdx.x >> 6;                       // layer 0..2
    int idx = (blockIdx.x & 63) * 256 + threadIdx.x; // 0..16383
    const float* W = lid == 0 ? W1 : (lid == 1 ? W2 : W3);
    int k = idx >> 7, n = idx & 127;
    float w = W[idx];
    u16 hi = f2bf(w);
    u16 lo = f2bf(w - bf2f(hi));
    wt[((size_t)lid * 2 + 0) * 16384 + (size_t)n * 128 + k] = hi;
    wt[((size_t)lid * 2 + 1) * 16384 + (size_t)n * 128 + k] = lo;
}

__global__ void xcast_k(const float* __restrict__ x, u16* __restrict__ xb) {
    int i = blockIdx.x * 256 + threadIdx.x;
    if (i < NN * DD / 4) {
        float4 v = ((const float4*)x)[i];
        ushort4 o;
        o.x = f2bf(v.x); o.y = f2bf(v.y); o.z = f2bf(v.z); o.w = f2bf(v.w);
        ((ushort4*)xb)[i] = o;
    }
}

// ---------------- MFMA GEMM: HB(bf16) = dis[row] * (act(A16) @ (Whi+Wlo)) ----------------
// 16x16x32 bf16 MFMA. A: row=lane&15, k=(lane>>4)*8+j. B: col=lane&15, same k.
// D: col=lane&15, row=(lane>>4)*4+reg.  BM=64 (4 waves x 16 rows), BN=128.

__global__ __launch_bounds__(256) void mgemm_k(const u16* __restrict__ A16,
                                               const u16* __restrict__ WT,  // [2][128][128]
                                               const float* __restrict__ sc,
                                               const float* __restrict__ sh,
                                               const float* __restrict__ dis,
                                               u16* __restrict__ HB, int use_bn) {
    __shared__ float scs[128], shs[128];
    int tid = threadIdx.x;
    if (use_bn && tid < 128) { scs[tid] = sc[tid]; shs[tid] = sh[tid]; }
    __syncthreads();
    int w = tid >> 6, lane = tid & 63;
    int col = lane & 15, lg = lane >> 4;
    int rowA = blockIdx.x * 64 + w * 16 + col;

    union { uint4 q; bf16x8 v; } afr[4];
#pragma unroll
    for (int s = 0; s < 4; s++) afr[s].q = make_uint4(0, 0, 0, 0);
    if (rowA < NN) {
        const uint4* ap = (const uint4*)(A16 + (size_t)rowA * DD);
#pragma unroll
        for (int s = 0; s < 4; s++) {
            uint4 q = ap[s * 4 + lg];
            if (use_bn) {
                unsigned uu[4] = {q.x, q.y, q.z, q.w};
                int cbase = s * 32 + lg * 8;
#pragma unroll
                for (int t = 0; t < 4; t++) {
                    int c0 = cbase + t * 2;
                    float f0 = fmaxf(fmaf(bf_lo(uu[t]), scs[c0], shs[c0]), 0.f);
                    float f1 = fmaxf(fmaf(bf_hi(uu[t]), scs[c0 + 1], shs[c0 + 1]), 0.f);
                    uu[t] = pack2bf(f0, f1);
                }
                q = make_uint4(uu[0], uu[1], uu[2], uu[3]);
            }
            afr[s].q = q;
        }
    }

    f32x4 acc[8];
#pragma unroll
    for (int cf = 0; cf < 8; cf++) { acc[cf][0] = 0.f; acc[cf][1] = 0.f; acc[cf][2] = 0.f; acc[cf][3] = 0.f; }

#pragma unroll
    for (int half = 0; half < 2; half++) {
        const u16* Wx = WT + (size_t)half * 16384;
#pragma unroll
        for (int s = 0; s < 4; s++) {
#pragma unroll
            for (int cf = 0; cf < 8; cf++) {
                bf16x8 b = *(const bf16x8*)(Wx + (size_t)(cf * 16 + col) * 128 + s * 32 + lg * 8);
                acc[cf] = __builtin_amdgcn_mfma_f32_16x16x32_bf16(afr[s].v, b, acc[cf], 0, 0, 0);
            }
        }
    }

#pragma unroll
    for (int r = 0; r < 4; r++) {
        int ro = blockIdx.x * 64 + w * 16 + lg * 4 + r;
        if (ro < NN) {
            float dv = dis[ro];
#pragma unroll
            for (int cf = 0; cf < 8; cf++) {
                HB[(size_t)ro * DD + cf * 16 + col] = f2bf(acc[cf][r] * dv);
            }
        }
    }
}

// ---------------- Gather (ELL, pre-scaled bf16 rows) + self-loop + bias + BN stats ----------------

__global__ __launch_bounds__(256) void gather_k(const u16* __restrict__ HB,
                                                const float* __restrict__ dis,
                                                const int* __restrict__ fc,
                                                const u16* __restrict__ ell,
                                                const float* __restrict__ bias,
                                                u16* __restrict__ AGG,
                                                float* __restrict__ stats) {
    __shared__ float s_sum[128], s_sq[128];
    int tid = threadIdx.x;
    if (tid < 128) { s_sum[tid] = 0.f; s_sq[tid] = 0.f; }
    __syncthreads();
    int lane = tid & 63;
    int wid = blockIdx.x * 4 + (tid >> 6);
    const int nwaves = GATHER_BLOCKS * 4;
    int c = lane * 2;
    float b0 = bias[c], b1 = bias[c + 1];
    float lsum0 = 0.f, lsum1 = 0.f, lsq0 = 0.f, lsq1 = 0.f;
    for (int v = wid; v < NN; v += nwaves) {
        int cntv = fc[v];
        if (cntv > ELLW) cntv = ELLW;
        int myidx = (lane < cntv) ? (int)ell[(size_t)v * ELLW + lane] : 0;
        float a0 = 0.f, a1 = 0.f;
        int j = 0;
        for (; j + 8 <= cntv; j += 8) {
            unsigned r[8];
#pragma unroll
            for (int q = 0; q < 8; q++) {
                int s = __shfl(myidx, j + q);
                r[q] = *(const unsigned*)(HB + (size_t)s * DD + c);
            }
#pragma unroll
            for (int q = 0; q < 8; q++) { a0 += bf_lo(r[q]); a1 += bf_hi(r[q]); }
        }
        for (; j < cntv; j++) {
            int s = __shfl(myidx, j);
            unsigned r0 = *(const unsigned*)(HB + (size_t)s * DD + c);
            a0 += bf_lo(r0);
            a1 += bf_hi(r0);
        }
        unsigned rsf = *(const unsigned*)(HB + (size_t)v * DD + c);
        float dv = dis[v];
        float o0 = fmaf(a0 + bf_lo(rsf), dv, b0);
        float o1 = fmaf(a1 + bf_hi(rsf), dv, b1);
        *(unsigned*)(AGG + (size_t)v * DD + c) = pack2bf(o0, o1);
        lsum0 += o0; lsum1 += o1;
        lsq0 += o0 * o0; lsq1 += o1 * o1;
    }
    atomicAdd(&s_sum[c], lsum0);
    atomicAdd(&s_sum[c + 1], lsum1);
    atomicAdd(&s_sq[c], lsq0);
    atomicAdd(&s_sq[c + 1], lsq1);
    __syncthreads();
    if (tid < 128) {
        atomicAdd(&stats[tid], s_sum[tid]);
        atomicAdd(&stats[128 + tid], s_sq[tid]);
    }
}

// ---------------- BN stats -> scale/shift ----------------

__global__ void bnfix_k(const float* __restrict__ stats, const float* __restrict__ g,
                        const float* __restrict__ be, float* __restrict__ sc,
                        float* __restrict__ sh) {
    int c = threadIdx.x;
    float mean = stats[c] * (1.0f / NN);
    float var = stats[128 + c] * (1.0f / NN) - mean * mean;
    float s = g[c] / sqrtf(var + BN_EPS);
    sc[c] = s;
    sh[c] = be[c] - mean * s;
}

// ---------------- Pool (bf16 agg) ----------------

__global__ __launch_bounds__(256) void pool_k(const u16* __restrict__ AGG,
                                              const int* __restrict__ batch,
                                              const float* __restrict__ sc,
                                              const float* __restrict__ sh,
                                              float* __restrict__ P) {
    int lane = threadIdx.x & 63;
    int wid = blockIdx.x * 4 + (threadIdx.x >> 6);
    int nw = gridDim.x * 4;
    int c = lane * 2;
    float sc0 = sc[c], sc1 = sc[c + 1], sh0 = sh[c], sh1 = sh[c + 1];
    int chunk = (NN + nw - 1) / nw;
    int v0 = wid * chunk, v1 = v0 + chunk;
    if (v1 > NN) v1 = NN;
    if (v0 >= NN) return;
    int curb = batch[v0];
    float acc0 = 0.f, acc1 = 0.f;
    for (int v = v0; v < v1; v++) {
        int b = batch[v];
        if (b != curb) {
            atomicAdd(&P[curb * 128 + c], acc0);
            atomicAdd(&P[curb * 128 + c + 1], acc1);
            acc0 = 0.f; acc1 = 0.f; curb = b;
        }
        unsigned hv = *(const unsigned*)(AGG + (size_t)v * DD + c);
        acc0 += fmaxf(fmaf(bf_lo(hv), sc0, sh0), 0.f);
        acc1 += fmaxf(fmaf(bf_hi(hv), sc1, sh1), 0.f);
    }
    atomicAdd(&P[curb * 128 + c], acc0);
    atomicAdd(&P[curb * 128 + c + 1], acc1);
}

// ---------------- Head ----------------

__global__ __launch_bounds__(128) void head_k(const float* __restrict__ P,
                                              const float* __restrict__ Wm1,
                                              const float* __restrict__ bm1,
                                              const float* __restrict__ Wm2,
                                              const float* __restrict__ bm2,
                                              float* __restrict__ OUT) {
    __shared__ float prow[128];
    __shared__ float red[128];
    int g = blockIdx.x, t = threadIdx.x;
    prow[t] = P[g * 128 + t];
    __syncthreads();
    float acc = bm1[t];
#pragma unroll 8
    for (int i = 0; i < 128; i++) acc = fmaf(prow[i], Wm1[i * 128 + t], acc);
    red[t] = fmaxf(acc, 0.f) * Wm2[t];
    __syncthreads();
    for (int off = 64; off > 0; off >>= 1) {
        if (t < off) red[t] += red[t + off];
        __syncthreads();
    }
    if (t == 0) OUT[g] = red[0] + bm2[0];
}

// ---------------- Launch ----------------

extern "C" void kernel_launch(void* const* d_in, const int* in_sizes, int n_in,
                              void* d_out, int out_size, void* d_ws, size_t ws_size,
                              hipStream_t stream) {
    const float* x   = (const float*)d_in[0];
    const int*  ei   = (const int*)d_in[1];
    const int*  batch= (const int*)d_in[2];
    const float* W1  = (const float*)d_in[3];
    const float* b1  = (const float*)d_in[4];
    const float* g1  = (const float*)d_in[5];
    const float* be1 = (const float*)d_in[6];
    const float* W2  = (const float*)d_in[7];
    const float* b2  = (const float*)d_in[8];
    const float* g2  = (const float*)d_in[9];
    const float* be2 = (const float*)d_in[10];
    const float* W3  = (const float*)d_in[11];
    const float* b3  = (const float*)d_in[12];
    const float* g3  = (const float*)d_in[13];
    const float* be3 = (const float*)d_in[14];
    const float* Wm1 = (const float*)d_in[15];
    const float* bm1 = (const float*)d_in[16];
    const float* Wm2 = (const float*)d_in[17];
    const float* bm2 = (const float*)d_in[18];
    float* out = (float*)d_out;

    char* ws = (char*)d_ws;
    size_t off = 0;
    auto alloc = [&](size_t bytes) -> void* {
        void* p = ws + off;
        off = (off + bytes + 255) & ~(size_t)255;
        return p;
    };
    int*   fc    = (int*)alloc((size_t)NN * 4);
    float* dis   = (float*)alloc((size_t)NN * 4);
    u16*   ell   = (u16*)alloc((size_t)NN * ELLW * 2);
    u16*   xb    = (u16*)alloc((size_t)NN * DD * 2);
    u16*   hb    = (u16*)alloc((size_t)NN * DD * 2);
    u16*   agg   = (u16*)alloc((size_t)NN * DD * 2);
    u16*   wt    = (u16*)alloc((size_t)3 * 2 * 16384 * 2);
    float* stats = (float*)alloc(3 * 256 * 4);
    float* scb   = (float*)alloc(3 * 128 * 4);
    float* shb   = (float*)alloc(3 * 128 * 4);
    float* p     = (float*)alloc((size_t)NG * DD * 4);

    const int* srcI = ei;
    const int* dstI = ei + NE;

    hipMemsetAsync(fc, 0, (size_t)NN * 4, stream);
    hipMemsetAsync(stats, 0, 3 * 256 * 4, stream);
    hipMemsetAsync(p, 0, (size_t)NG * DD * 4, stream);

    fillell_k<<<(NE + 255) / 256, 256, 0, stream>>>(srcI, dstI, fc, ell);
    dis_k<<<(NN + 255) / 256, 256, 0, stream>>>(fc, dis);
    wprep_k<<<192, 256, 0, stream>>>(W1, W2, W3, wt);
    xcast_k<<<(NN * DD / 4 + 255) / 256, 256, 0, stream>>>(x, xb);

    const int GB = (NN + 63) / 64;

    // Layer 1
    mgemm_k<<<GB, 256, 0, stream>>>(xb, wt, nullptr, nullptr, dis, hb, 0);
    gather_k<<<GATHER_BLOCKS, 256, 0, stream>>>(hb, dis, fc, ell, b1, agg, stats);
    bnfix_k<<<1, 128, 0, stream>>>(stats, g1, be1, scb, shb);

    // Layer 2
    mgemm_k<<<GB, 256, 0, stream>>>(agg, wt + 2 * 16384, scb, shb, dis, hb, 1);
    gather_k<<<GATHER_BLOCKS, 256, 0, stream>>>(hb, dis, fc, ell, b2, agg, stats + 256);
    bnfix_k<<<1, 128, 0, stream>>>(stats + 256, g2, be2, scb + 128, shb + 128);

    // Layer 3
    mgemm_k<<<GB, 256, 0, stream>>>(agg, wt + 4 * 16384, scb + 128, shb + 128, dis, hb, 1);
    gather_k<<<GATHER_BLOCKS, 256, 0, stream>>>(hb, dis, fc, ell, b3, agg, stats + 512);
    bnfix_k<<<1, 128, 0, stream>>>(stats + 512, g3, be3, scb + 256, shb + 256);

    // Pool + head
    pool_k<<<128, 256, 0, stream>>>(agg, batch, scb + 256, shb + 256, p);
    head_k<<<NG, 128, 0, stream>>>(p, Wm1, bm1, Wm2, bm2, out);
}